// Round 3
// baseline (727.510 us; speedup 1.0000x reference)
//
#include <hip/hip_runtime.h>
#include <hip/hip_bf16.h>

typedef __hip_bfloat16 bf16;
typedef short s16x8 __attribute__((ext_vector_type(8)));
typedef float f32x4 __attribute__((ext_vector_type(4)));
typedef int   i32x4 __attribute__((ext_vector_type(4)));

// B=4 N=2048 E=512 H=8 K=128 D=192, D1=1536, tokens=8192, FFT length 8192

static __device__ __forceinline__ float silu_f(float v){
  return v / (1.f + __expf(-v));
}

// ---------------- converts ----------------
__global__ void f2b_kernel(const float* __restrict__ in, bf16* __restrict__ out, int n){
  int i = blockIdx.x * blockDim.x + threadIdx.x;
  if (i < n) out[i] = __float2bfloat16(in[i]);
}

// split: hi = bf16(v), lo = bf16(v - float(hi))
__global__ void f2b_split_kernel(const float* __restrict__ in, bf16* __restrict__ hi,
                                 bf16* __restrict__ lo, int n){
  int i = blockIdx.x * blockDim.x + threadIdx.x;
  if (i < n){
    float v = in[i];
    bf16 h = __float2bfloat16(v);
    hi[i] = h;
    lo[i] = __float2bfloat16(v - __bfloat162float(h));
  }
}

// ct[hd*128 + k] = coef[h, k, d]   (coef: (8,128,192), hd = h*192 + d)
__global__ void coefT_split_kernel(const float* __restrict__ coef, bf16* __restrict__ hi,
                                   bf16* __restrict__ lo){
  int i = blockIdx.x * blockDim.x + threadIdx.x;
  if (i < 1536 * 128){
    int hd = i >> 7, k = i & 127;
    int h = hd / 192, dd = hd - h * 192;
    float v = coef[(h * 128 + k) * 192 + dd];
    bf16 hb = __float2bfloat16(v);
    hi[i] = hb;
    lo[i] = __float2bfloat16(v - __bfloat162float(hb));
  }
}

// vander (4095,128) fp32 -> (4096,128) bf16 hi/lo, last row zero
__global__ void vander_pad_split_kernel(const float* __restrict__ vander, bf16* __restrict__ hi,
                                        bf16* __restrict__ lo){
  int i = blockIdx.x * blockDim.x + threadIdx.x;
  if (i < 4096 * 128){
    float v = (i >> 7) < 4095 ? vander[i] : 0.f;
    bf16 hb = __float2bfloat16(v);
    hi[i] = hb;
    lo[i] = __float2bfloat16(v - __bfloat162float(hb));
  }
}

// ---------------- GEMM: C = A(MxK) @ Bt(NxK)^T, bf16 in, fp32 acc ----------------
// 128x128 tile, BK=32, 256 threads = 4 waves (2x2), 64x64/wave, 16x16x32 MFMA.
// nph=3: bf16x3 split  acc = Ahi*Bhi + Ahi*Blo + Alo*Bhi   (fp32-grade precision)
// mode 0: silu(val+bias), col<1536 -> out0 bf16 (u), col>=1536 -> out1 bf16 (v), both ld 1536
// mode 1: fp32 store out0[row*N+col]
// mode 2: fp32 store out0[row*N+col] = val + bias0[col]
__global__ __launch_bounds__(256)
void gemm_bf16(const bf16* __restrict__ A, const bf16* __restrict__ Alo,
               const bf16* __restrict__ Bt, const bf16* __restrict__ Btlo,
               int K, int N, int nph, int mode,
               const float* __restrict__ bias0, const float* __restrict__ bias1,
               void* __restrict__ out0, void* __restrict__ out1)
{
  __shared__ bf16 As[128 * 32];
  __shared__ bf16 Bs[128 * 32];
  const int tid  = threadIdx.x;
  const int lane = tid & 63;
  const int wave = tid >> 6;
  const int wr = wave >> 1, wc = wave & 1;
  const int bm = blockIdx.y * 128;
  const int bn = blockIdx.x * 128;

  const int c0i = tid, c1i = tid + 256;
  const int rA0 = c0i >> 2, cA0 = (c0i & 3) << 3;
  const int rA1 = c1i >> 2, cA1 = (c1i & 3) << 3;

  f32x4 acc[4][4];
#pragma unroll
  for (int i = 0; i < 4; i++)
#pragma unroll
    for (int j = 0; j < 4; j++) acc[i][j] = (f32x4){0.f, 0.f, 0.f, 0.f};

  const int laneRow = lane & 15;
  const int laneK   = (lane >> 4) << 3;

  for (int ph = 0; ph < nph; ++ph){
    const bf16* Ap = (ph == 2) ? Alo  : A;
    const bf16* Bp = (ph == 1) ? Btlo : Bt;
    const bf16* Ab = Ap + (size_t)bm * K;
    const bf16* Bb = Bp + (size_t)bn * K;
    for (int k0 = 0; k0 < K; k0 += 32){
      i32x4 a0 = *(const i32x4*)(Ab + (size_t)rA0 * K + k0 + cA0);
      i32x4 a1 = *(const i32x4*)(Ab + (size_t)rA1 * K + k0 + cA1);
      i32x4 b0 = *(const i32x4*)(Bb + (size_t)rA0 * K + k0 + cA0);
      i32x4 b1 = *(const i32x4*)(Bb + (size_t)rA1 * K + k0 + cA1);
      __syncthreads();                     // prior iteration's LDS reads done
      *(i32x4*)(As + c0i * 8) = a0;
      *(i32x4*)(As + c1i * 8) = a1;
      *(i32x4*)(Bs + c0i * 8) = b0;
      *(i32x4*)(Bs + c1i * 8) = b1;
      __syncthreads();
      s16x8 af[4], bv[4];
#pragma unroll
      for (int mi = 0; mi < 4; mi++)
        af[mi] = *(const s16x8*)(As + (wr * 64 + mi * 16 + laneRow) * 32 + laneK);
#pragma unroll
      for (int ni = 0; ni < 4; ni++)
        bv[ni] = *(const s16x8*)(Bs + (wc * 64 + ni * 16 + laneRow) * 32 + laneK);
#pragma unroll
      for (int mi = 0; mi < 4; mi++)
#pragma unroll
        for (int ni = 0; ni < 4; ni++)
          acc[mi][ni] = __builtin_amdgcn_mfma_f32_16x16x32_bf16(af[mi], bv[ni], acc[mi][ni], 0, 0, 0);
    }
  }

  const int rowOff = (lane >> 4) << 2;   // C/D: col = lane&15, row = (lane>>4)*4 + reg
#pragma unroll
  for (int mi = 0; mi < 4; mi++){
    const int rowb = bm + wr * 64 + mi * 16 + rowOff;
#pragma unroll
    for (int ni = 0; ni < 4; ni++){
      const int col = bn + wc * 64 + ni * 16 + laneRow;
#pragma unroll
      for (int r = 0; r < 4; r++){
        const int row = rowb + r;
        float val = acc[mi][ni][r];
        if (mode == 0){
          float bsv = (col < 1536) ? bias0[col] : bias1[col - 1536];
          val = silu_f(val + bsv);
          if (col < 1536) ((bf16*)out0)[(size_t)row * 1536 + col] = __float2bfloat16(val);
          else            ((bf16*)out1)[(size_t)row * 1536 + (col - 1536)] = __float2bfloat16(val);
        } else if (mode == 1){
          ((float*)out0)[(size_t)row * N + col] = val;
        } else {
          ((float*)out0)[(size_t)row * N + col] = val + bias0[col];
        }
      }
    }
  }
}

// ---------------- transpose v (8192 x 1536, row=(b,i), col=hd) -> v_t[(b*1536+hd)*2048 + i]
__global__ void transpose_v_kernel(const bf16* __restrict__ v_nat, bf16* __restrict__ v_t){
  __shared__ bf16 tile[32][33];
  const int tx = threadIdx.x & 31, ty = threadIdx.x >> 5;
  const int c0 = blockIdx.x * 32;      // hd
  const int r0 = blockIdx.y * 32;      // token row (2048 % 32 == 0 so one b per block)
  const int b  = r0 >> 11;
  const int i0 = r0 & 2047;
#pragma unroll
  for (int yy = ty; yy < 32; yy += 8)
    tile[yy][tx] = v_nat[(size_t)(r0 + yy) * 1536 + c0 + tx];
  __syncthreads();
#pragma unroll
  for (int yy = ty; yy < 32; yy += 8)
    v_t[((size_t)b * 1536 + c0 + yy) * 2048 + i0 + tx] = tile[tx][yy];
}

// ---------------- gate: gateA[(b,i),hd] = u * conv   (conv layout (b,hd,i))
__global__ void gate_kernel(const bf16* __restrict__ u_bf, const bf16* __restrict__ conv_t,
                            bf16* __restrict__ gateA){
  __shared__ bf16 tile[32][33];
  const int tx = threadIdx.x & 31, ty = threadIdx.x >> 5;
  const int c0 = blockIdx.x * 32;
  const int r0 = blockIdx.y * 32;
  const int b  = r0 >> 11;
  const int i0 = r0 & 2047;
#pragma unroll
  for (int yy = ty; yy < 32; yy += 8)
    tile[yy][tx] = conv_t[((size_t)b * 1536 + c0 + yy) * 2048 + i0 + tx];
  __syncthreads();
#pragma unroll
  for (int yy = ty; yy < 32; yy += 8){
    const size_t idx = (size_t)(r0 + yy) * 1536 + c0 + tx;
    float g = __bfloat162float(u_bf[idx]) * __bfloat162float(tile[tx][yy]);
    gateA[idx] = __float2bfloat16(g);
  }
}

// ---------------- FFT conv ----------------
// in-place radix-2 DIT, 8192 complex, 512 threads, sign=-1 fwd / +1 inv (unscaled)
__device__ __forceinline__ void fft8192(float2* buf, int tid, float sign){
#pragma unroll
  for (int s = 0; s < 16; s++){
    int i = tid + s * 512;
    int r = (int)(__brev((unsigned)i) >> 19);
    if (r > i){ float2 tmp = buf[i]; buf[i] = buf[r]; buf[r] = tmp; }
  }
  __syncthreads();
  for (int half = 1; half < 8192; half <<= 1){
    const float cstep = sign * 3.14159265358979323846f / (float)half;
    for (int bb = tid; bb < 4096; bb += 512){
      const int j  = bb & (half - 1);
      const int i0 = ((bb & ~(half - 1)) << 1) + j;
      const int i1 = i0 + half;
      float sn, cs;
      __sincosf(cstep * (float)j, &sn, &cs);
      float2 a = buf[i0], c = buf[i1];
      float tx = cs * c.x - sn * c.y;
      float ty = cs * c.y + sn * c.x;
      float2 lo, hi;
      lo.x = a.x + tx; lo.y = a.y + ty;
      hi.x = a.x - tx; hi.y = a.y - ty;
      buf[i0] = lo; buf[i1] = hi;
    }
    __syncthreads();
  }
}

// one block per hd; filter spectrum cached in regs; batches packed 2-at-a-time (filter real)
__global__ __launch_bounds__(512)
void conv_fft_kernel(const float* __restrict__ t_time, const bf16* __restrict__ v_t,
                     bf16* __restrict__ conv_t){
  __shared__ float2 buf[8192];   // 64 KB
  const int tid = threadIdx.x;
  const int hd  = blockIdx.x;

  const float* trow = t_time + (size_t)hd * 4096;
  for (int i = tid; i < 8192; i += 512){
    float2 z; z.x = (i < 4096) ? trow[i] : 0.f; z.y = 0.f;
    buf[i] = z;
  }
  __syncthreads();
  fft8192(buf, tid, -1.f);
  float2 Treg[16];
#pragma unroll
  for (int s = 0; s < 16; s++) Treg[s] = buf[tid + s * 512];
  __syncthreads();

  for (int pair = 0; pair < 2; pair++){
    const bf16* v0 = v_t + ((size_t)(2 * pair)     * 1536 + hd) * 2048;
    const bf16* v1 = v_t + ((size_t)(2 * pair + 1) * 1536 + hd) * 2048;
    for (int i = tid; i < 8192; i += 512){
      float2 z;
      if (i < 2048){ z.x = __bfloat162float(v0[i]); z.y = __bfloat162float(v1[i]); }
      else         { z.x = 0.f; z.y = 0.f; }
      buf[i] = z;
    }
    __syncthreads();
    fft8192(buf, tid, -1.f);
#pragma unroll
    for (int s = 0; s < 16; s++){
      int k = tid + s * 512;
      float2 Z = buf[k], T = Treg[s];
      float2 W;
      W.x = Z.x * T.x - Z.y * T.y;
      W.y = Z.x * T.y + Z.y * T.x;
      buf[k] = W;
    }
    __syncthreads();
    fft8192(buf, tid, 1.f);
    bf16* c0 = conv_t + ((size_t)(2 * pair)     * 1536 + hd) * 2048;
    bf16* c1 = conv_t + ((size_t)(2 * pair + 1) * 1536 + hd) * 2048;
    const float inv = 1.f / 8192.f;
    for (int i = tid; i < 2048; i += 512){
      float2 w = buf[2047 + i];      // window tau = 2047+i: exact linear conv (no wrap at L=8192)
      c0[i] = __float2bfloat16(w.x * inv);
      c1[i] = __float2bfloat16(w.y * inv);
    }
    __syncthreads();
  }
}

extern "C" void kernel_launch(void* const* d_in, const int* in_sizes, int n_in,
                              void* d_out, int out_size, void* d_ws, size_t ws_size,
                              hipStream_t stream)
{
  (void)in_sizes; (void)n_in; (void)out_size; (void)ws_size;
  const float* x      = (const float*)d_in[0];
  const float* vander = (const float*)d_in[1];
  // d_in[2] = index (Toeplitz gather indices) — unused
  const float* coef   = (const float*)d_in[3];
  const float* Wu     = (const float*)d_in[4];
  const float* bu     = (const float*)d_in[5];
  const float* Wv     = (const float*)d_in[6];
  const float* bv     = (const float*)d_in[7];
  const float* Wo     = (const float*)d_in[8];
  const float* bo     = (const float*)d_in[9];

  char* ws = (char*)d_ws;
  size_t off = 0;
  auto alloc = [&](size_t bytes) -> void* { void* p = ws + off; off += bytes; return p; };

  bf16*  xb_hi  = (bf16*) alloc((size_t)8192 * 512 * 2);
  bf16*  xb_lo  = (bf16*) alloc((size_t)8192 * 512 * 2);
  bf16*  wuv_hi = (bf16*) alloc((size_t)3072 * 512 * 2);
  bf16*  wuv_lo = (bf16*) alloc((size_t)3072 * 512 * 2);
  bf16*  wo_b   = (bf16*) alloc((size_t)512 * 1536 * 2);
  bf16*  ct_hi  = (bf16*) alloc((size_t)1536 * 128 * 2);
  bf16*  ct_lo  = (bf16*) alloc((size_t)1536 * 128 * 2);
  bf16*  vb_hi  = (bf16*) alloc((size_t)4096 * 128 * 2);
  bf16*  vb_lo  = (bf16*) alloc((size_t)4096 * 128 * 2);
  bf16*  u_bf   = (bf16*) alloc((size_t)8192 * 1536 * 2);
  bf16*  v_bf   = (bf16*) alloc((size_t)8192 * 1536 * 2);   // (token, hd); reused as conv_t
  bf16*  v_t    = (bf16*) alloc((size_t)8192 * 1536 * 2);   // (b, hd, i)
  float* t_time = (float*)alloc((size_t)1536 * 4096 * 4);   // reused as gateA

  bf16* conv_t = v_bf;            // v_bf dead after transpose
  bf16* gateA  = (bf16*)t_time;   // t_time dead after conv kernel

  f2b_split_kernel<<<16384, 256, 0, stream>>>(x, xb_hi, xb_lo, 4194304);
  f2b_split_kernel<<<3072, 256, 0, stream>>>(Wu, wuv_hi, wuv_lo, 786432);
  f2b_split_kernel<<<3072, 256, 0, stream>>>(Wv, wuv_hi + 786432, wuv_lo + 786432, 786432);
  f2b_kernel<<<3072, 256, 0, stream>>>(Wo, wo_b, 786432);
  coefT_split_kernel<<<768, 256, 0, stream>>>(coef, ct_hi, ct_lo);
  vander_pad_split_kernel<<<2048, 256, 0, stream>>>(vander, vb_hi, vb_lo);

  // G1 (bf16x3): [u|v] = silu(x @ [Wu;Wv]^T + b)   (8192 x 3072, K=512)
  gemm_bf16<<<dim3(24, 64), 256, 0, stream>>>(xb_hi, xb_lo, wuv_hi, wuv_lo,
                                              512, 3072, 3, 0, bu, bv, u_bf, v_bf);
  transpose_v_kernel<<<dim3(48, 256), 256, 0, stream>>>(v_bf, v_t);
  // G2 (bf16x3): t[hd, m] = sum_k coef^T[hd,k] * vander[m,k]   (1536 x 4096, K=128)
  gemm_bf16<<<dim3(32, 12), 256, 0, stream>>>(ct_hi, ct_lo, vb_hi, vb_lo,
                                              128, 4096, 3, 1, nullptr, nullptr, t_time, nullptr);
  // FFT convolution per hd channel
  conv_fft_kernel<<<1536, 512, 0, stream>>>(t_time, v_t, conv_t);
  // gate: A = u * conv  (back to (token, hd) layout)
  gate_kernel<<<dim3(48, 256), 256, 0, stream>>>(u_bf, conv_t, gateA);
  // G3: out = A @ Wo^T + bo  (8192 x 512, K=1536), fp32 store to d_out
  gemm_bf16<<<dim3(4, 64), 256, 0, stream>>>(gateA, gateA, wo_b, wo_b,
                                             1536, 512, 1, 2, bo, nullptr, d_out, nullptr);
}